// Round 9
// baseline (5842.210 us; speedup 1.0000x reference)
//
#include <hip/hip_runtime.h>
#include <cstdint>
#include <cstddef>

// SokobanNCA v9: identical to v8 except __launch_bounds__(512, 2).
// v8's allocator capped at 64 VGPR (spilled ~40 regs: WRITE 413MB, FETCH 3GB).
// (512,2) raises the cap above the ~105-reg live set while LDS (63KB) still
// allows 2 blocks/CU = 16 waves/CU latency-hiding pool.

#define NSAMPLES 2048
#define ZROW_BASE 28672          // 112*256
#define HA_OFF 0
#define HB_OFF 28928             // 113*256
#define A1_OFF HB_OFF            // A1 aliases hB (disjoint lifetime)
#define XS_OFF 57600             // HB_OFF + 112*256
#define LDS_TOTAL 62976          // XS_OFF + 112*48

typedef __attribute__((ext_vector_type(8))) short bf16x8;
typedef __attribute__((ext_vector_type(4))) float f32x4;
typedef __attribute__((ext_vector_type(2))) unsigned int u32x2;
typedef __attribute__((ext_vector_type(4))) unsigned int u32x4;

#define MFMA16(A,B,C) __builtin_amdgcn_mfma_f32_16x16x32_bf16((A),(B),(C),0,0,0)

__device__ __forceinline__ unsigned pk2(float a, float b) {
  unsigned r;
  asm("v_cvt_pk_bf16_f32 %0, %1, %2" : "=v"(r) : "v"(a), "v"(b));
  return r;
}
__device__ __forceinline__ unsigned pk2r(float a, float b) {
  return pk2(fmaxf(a, 0.f), fmaxf(b, 0.f));
}

__device__ __forceinline__ short f2bf(float f) {
  unsigned u = __float_as_uint(f);
  return (short)((u + 0x7FFFu + ((u >> 16) & 1u)) >> 16);  // RNE
}

// ---------------- weight pre-pack (unchanged; validated r1-r8) ----------------
__global__ void prepack_kernel(const float* __restrict__ w, short* __restrict__ dst,
                               int mode, int ntc, int Kact, int Nact, int total) {
  int idx = blockIdx.x * 256 + threadIdx.x;
  if (idx >= total) return;
  int j = idx & 7, l = (idx >> 3) & 63, t = idx >> 9;
  int nt = t % ntc, kt = t / ntc;
  int kg = kt * 32 + (l >> 4) * 8 + j;
  int nn = nt * 16 + (l & 15);
  float v = 0.f;
  if (mode == 0) {
    if (kg < Kact && nn < Nact) v = w[nn * Kact + kg];
  } else if (mode == 1) {
    if (kg < 45) { int s = kg / 5, cin = kg - 5 * s; v = w[nn * 45 + cin * 9 + s]; }
  } else {
    int s = kt >> 2;
    int kk = (kt & 3) * 32 + (l >> 4) * 8 + j;
    v = w[nn * 1152 + kk * 9 + s];
  }
  dst[idx] = f2bf(v);
}

// ---------------- device helpers ----------------
__device__ __forceinline__ void load_w4(bf16x8 (&W)[2][4], const short* __restrict__ p,
                                        int wc, int l) {
#pragma unroll
  for (int mt = 0; mt < 2; ++mt)
#pragma unroll
    for (int kt = 0; kt < 4; ++kt)
      W[mt][kt] = *(const bf16x8*)&p[((kt * 8 + 2 * wc + mt) * 64 + l) * 8];
}
__device__ __forceinline__ void load_b(f32x4 (&pb)[2], const float* __restrict__ bp,
                                       int wc, int g) {
  pb[0] = *(const f32x4*)&bp[16 * (2 * wc) + 4 * g];
  pb[1] = *(const f32x4*)&bp[16 * (2 * wc + 1) + 4 * g];
}

// store own qt tiles, both cout tiles of this wc
__device__ __forceinline__ void store_half(const f32x4 (&acc)[2][4], char* lds, int dsto,
                                           int qtb, int n, int nq, int wcol0, int wcol1) {
#pragma unroll
  for (int qtl = 0; qtl < 4; ++qtl) {
    if (qtl < nq) {
      int row = (16 * (qtb + qtl) + n) * 256;
      {
        f32x4 v = acc[0][qtl];
        u32x2 wv = {pk2r(v.x, v.y), pk2r(v.z, v.w)};
        *(u32x2*)(lds + dsto + row + wcol0) = wv;
      }
      {
        f32x4 v = acc[1][qtl];
        u32x2 wv = {pk2r(v.x, v.y), pk2r(v.z, v.w)};
        *(u32x2*)(lds + dsto + row + wcol1) = wv;
      }
    }
  }
}

// ---------------- main kernel ----------------
__global__ __launch_bounds__(512, 2)
void nca_kernel(
    const float* __restrict__ x_in,
    const float* __restrict__ b1p, const float* __restrict__ b2p,
    const float* __restrict__ b3p, const float* __restrict__ b4p,
    const float* __restrict__ b5p, const float* __restrict__ b6p,
    const float* __restrict__ b7p,
    const short* __restrict__ W1, const short* __restrict__ W2,
    const short* __restrict__ W3,   // W3..W6 contiguous: W3 + li*16384
    const short* __restrict__ W7,
    const int* __restrict__ steps_ptr, float* __restrict__ d_out) {
  __shared__ __align__(16) char lds[LDS_TOTAL];
  float* xs = (float*)(lds + XS_OFF);  // [112][12] f32, rows 48 B

  const int tid = threadIdx.x;
  const int sample = blockIdx.x;
  const int w  = tid >> 6;        // wave 0..7
  const int wc = w >> 1;          // cout group: tiles {2wc, 2wc+1}
  const int wp = w & 1;           // pixel half
  const int l = tid & 63;
  const int n = l & 15;
  const int g = l >> 4;
  const int g16 = g << 4;
  const int swzc = (n & 7) << 4;
  const int qtb = wp * 4;         // owned qt base
  const int nq  = wp ? 3 : 4;     // owned qt count
  const int steps = *steps_ptr;
  const float steps_f = (float)steps;
  const f32x4 fz = {0.f, 0.f, 0.f, 0.f};

  // LDS bases (layout identical to r3-r8)
  const int rdA = HA_OFF + n * 256 + (g16 ^ swzc);
  const int rdB = HB_OFF + n * 256 + (g16 ^ swzc);
  const int rd1 = A1_OFF + n * 128 + (g16 ^ swzc);
  const int za  = HA_OFF + ZROW_BASE + g16;
  const int wcol0 = ((32 * (2 * wc)) | (8 * g)) ^ swzc;
  const int wcol1 = ((32 * (2 * wc + 1)) | (8 * g)) ^ swzc;

  // per-owned-qt pixel geometry (c2 shift masking)
  int rcq[4];
#pragma unroll
  for (int qtl = 0; qtl < 4; ++qtl) {
    int p = 16 * (qtb + qtl) + n;
    if (qtl < nq && p < 100) { int r = p / 10; rcq[qtl] = r * 32 + (p - 10 * r); }
    else rcq[qtl] = 0x4000;
  }
  // (c,px) decomposition for 500-elem copies (512 threads: single pass)
  const int c5 = tid < 500 ? tid / 100 : 4;
  const int p5 = tid - 100 * c5;
  const int off5 = p5 * 12 + c5;

  // zero ZROW of hA
  if (tid < 64) *(unsigned*)(lds + HA_OFF + ZROW_BASE + tid * 4) = 0;
  // load x state
  if (tid < 500) xs[off5] = x_in[(size_t)sample * 500 + tid];
  // persistent c7 weights + bias
  bf16x8 W7f[4];
#pragma unroll
  for (int kt = 0; kt < 4; ++kt)
    W7f[kt] = *(const bf16x8*)&W7[(kt * 64 + l) * 8];
  f32x4 b7v = fz;
  if (g == 0) b7v = *(const f32x4*)&b7p[0];
  else if (g == 1) b7v.x = b7p[4];
  __syncthreads();

  for (int step = 0; step < steps; ++step) {
    // ---- phase A: copy out states[step-1]; build im2col (r6-validated) ----
    if (step > 0 && tid < 500) {
      size_t sb = 1024000u + ((size_t)(step - 1) * NSAMPLES + sample) * 500u;
      __builtin_nontemporal_store(xs[off5], &d_out[sb + tid]);
    }
    if (tid < 112) {
      const int p = tid;
      const bool pv = p < 100;
      const int pc = pv ? p : 99;
      const int r = pc / 10, c0 = pc - 10 * r;
      float val[48];
#pragma unroll
      for (int s = 0; s < 9; ++s) {
        const int dr = s / 3 - 1, dc = s % 3 - 1;
        f32x4 xv = fz; float x4v = 0.f;
        if (pv && (unsigned)(r + dr) < 10u && (unsigned)(c0 + dc) < 10u) {
          const float* xr = &xs[(p + dr * 10 + dc) * 12];
          xv = *(const f32x4*)xr; x4v = xr[4];
        }
        val[5*s+0] = xv.x; val[5*s+1] = xv.y; val[5*s+2] = xv.z;
        val[5*s+3] = xv.w; val[5*s+4] = x4v;
      }
      val[45] = val[46] = val[47] = 0.f;
      unsigned wd[24];
#pragma unroll
      for (int i = 0; i < 24; ++i) wd[i] = pk2(val[2*i], val[2*i+1]);
      const int swzr = (p & 7) << 4;
      char* arow = lds + A1_OFF + p * 128;
#pragma unroll
      for (int j = 0; j < 6; ++j) {
        u32x4 wv = {wd[4*j], wd[4*j+1], wd[4*j+2], wd[4*j+3]};
        *(u32x4*)(arow + ((16 * j) ^ swzr)) = wv;
      }
      u32x4 z4 = {0, 0, 0, 0};
      *(u32x4*)(arow + (96 ^ swzr)) = z4;
      *(u32x4*)(arow + (112 ^ swzr)) = z4;
    }
    __syncthreads();

    // ---- c1: A1 @ W1 (K=64) -> hA (own qt, own cout tiles) ----
    {
      bf16x8 Wf[2][2];
#pragma unroll
      for (int mt = 0; mt < 2; ++mt)
#pragma unroll
        for (int kt = 0; kt < 2; ++kt)
          Wf[mt][kt] = *(const bf16x8*)&W1[((kt * 8 + 2 * wc + mt) * 64 + l) * 8];
      f32x4 pb[2];
      load_b(pb, b1p, wc, g);
      f32x4 acc[2][4];
#pragma unroll
      for (int qtl = 0; qtl < 4; ++qtl) { acc[0][qtl] = pb[0]; acc[1][qtl] = pb[1]; }
#pragma unroll
      for (int kt = 0; kt < 2; ++kt) {
        const char* src = lds + (rd1 ^ (kt << 6));
#pragma unroll
        for (int qtl = 0; qtl < 4; ++qtl) {
          if (qtl < nq) {
            bf16x8 Bf = *(const bf16x8*)(src + (qtb + qtl) * 2048);
            acc[0][qtl] = MFMA16(Wf[0][kt], Bf, acc[0][qtl]);
            acc[1][qtl] = MFMA16(Wf[1][kt], Bf, acc[1][qtl]);
          }
        }
      }
      store_half(acc, lds, HA_OFF, qtb, n, nq, wcol0, wcol1);
    }
    __syncthreads();

    // ---- c2: 3x3 shift-decomposed, runtime s-loop ----
    {
      f32x4 acc[2][4];
      {
        f32x4 pb[2];
        load_b(pb, b2p, wc, g);
#pragma unroll
        for (int qtl = 0; qtl < 4; ++qtl) { acc[0][qtl] = pb[0]; acc[1][qtl] = pb[1]; }
      }
#pragma unroll 1
      for (int s = 0; s < 9; ++s) {
        const int s3 = s / 3;
        const int dr = s3 - 1, dc = s - 3 * s3 - 1;
        bf16x8 Wf[2][4];
        load_w4(Wf, W2 + s * 16384, wc, l);
        const int ps = n + dr * 10 + dc;
        const int bs = HA_OFF + ps * 256 + (g16 ^ ((ps & 7) << 4));
#pragma unroll
        for (int qtl = 0; qtl < 4; ++qtl) {
          if (qtl < nq) {
            bool ok = ((unsigned)((rcq[qtl] >> 5) + dr) < 10u) &&
                      ((unsigned)((rcq[qtl] & 31) + dc) < 10u);
            int va = ok ? (bs + (qtb + qtl) * 4096) : za;
#pragma unroll
            for (int kt = 0; kt < 4; ++kt) {
              bf16x8 Bf = *(const bf16x8*)(lds + (va ^ (kt << 6)));
              acc[0][qtl] = MFMA16(Wf[0][kt], Bf, acc[0][qtl]);
              acc[1][qtl] = MFMA16(Wf[1][kt], Bf, acc[1][qtl]);
            }
          }
        }
      }
      store_half(acc, lds, HB_OFF, qtb, n, nq, wcol0, wcol1);
    }
    __syncthreads();

    // ---- c3..c6: runtime layer loop, ping-pong hB<->hA ----
#pragma unroll 1
    for (int li = 0; li < 4; ++li) {
      const float* bp = (li == 0) ? b3p : (li == 1) ? b4p : (li == 2) ? b5p : b6p;
      const int rdb = (li & 1) ? rdA : rdB;
      const int dsto = (li & 1) ? HB_OFF : HA_OFF;
      bf16x8 Wf[2][4];
      load_w4(Wf, W3 + li * 16384, wc, l);
      f32x4 pb[2];
      load_b(pb, bp, wc, g);
      f32x4 acc[2][4];
#pragma unroll
      for (int qtl = 0; qtl < 4; ++qtl) { acc[0][qtl] = pb[0]; acc[1][qtl] = pb[1]; }
#pragma unroll
      for (int kt = 0; kt < 4; ++kt) {
        const char* src = lds + (rdb ^ (kt << 6));
#pragma unroll
        for (int qtl = 0; qtl < 4; ++qtl) {
          if (qtl < nq) {
            bf16x8 Bf = *(const bf16x8*)(src + (qtb + qtl) * 4096);
            acc[0][qtl] = MFMA16(Wf[0][kt], Bf, acc[0][qtl]);
            acc[1][qtl] = MFMA16(Wf[1][kt], Bf, acc[1][qtl]);
          }
        }
      }
      store_half(acc, lds, dsto, qtb, n, nq, wcol0, wcol1);
      __syncthreads();
    }

    // ---- c7 (128->5): wave w handles qt=w (w<7); residual + softmax ----
    {
      float invT = 1.f / fmaxf(1.f - (float)step / steps_f, 0.5f);
      if (w < 7) {
        f32x4 a = b7v;
        int va7 = rdB + w * 4096;
#pragma unroll
        for (int kt = 0; kt < 4; ++kt) {
          bf16x8 Bf = *(const bf16x8*)(lds + (va7 ^ (kt << 6)));
          a = MFMA16(W7f[kt], Bf, a);
        }
        float c4v = __shfl_xor(a.x, 16);
        int px = 16 * w + n;
        if (g == 0 && px < 100) {
          float* xr = &xs[px * 12];
          f32x4 xo = *(f32x4*)xr; float x4 = xr[4];
          float v0 = (xo.x + a.x) * invT, v1 = (xo.y + a.y) * invT;
          float v2 = (xo.z + a.z) * invT, v3 = (xo.w + a.w) * invT;
          float v4 = (x4 + c4v) * invT;
          float m = fmaxf(fmaxf(fmaxf(v0, v1), fmaxf(v2, v3)), v4);
          float e0 = __expf(v0 - m), e1 = __expf(v1 - m), e2 = __expf(v2 - m);
          float e3 = __expf(v3 - m), e4 = __expf(v4 - m);
          float inv = 1.f / (e0 + e1 + e2 + e3 + e4);
          f32x4 pv = {e0 * inv, e1 * inv, e2 * inv, e3 * inv};
          *(f32x4*)xr = pv; xr[4] = e4 * inv;
        }
      }
    }
    __syncthreads();
  }

  // ---- final outputs: x_final + states[steps-1] (nontemporal) ----
  if (tid < 500) {
    size_t sb = 1024000u + ((size_t)(steps - 1) * NSAMPLES + sample) * 500u;
    size_t fb = (size_t)sample * 500u;
    float v = xs[off5];
    __builtin_nontemporal_store(v, &d_out[fb + tid]);
    __builtin_nontemporal_store(v, &d_out[sb + tid]);
  }
}

// ---------------- launch ----------------
extern "C" void kernel_launch(void* const* d_in, const int* in_sizes, int n_in,
                              void* d_out, int out_size, void* d_ws, size_t ws_size,
                              hipStream_t stream) {
  const float* x   = (const float*)d_in[0];
  const float* wp1 = (const float*)d_in[1];
  const float* bp1 = (const float*)d_in[2];
  const float* wp2 = (const float*)d_in[3];
  const float* bp2 = (const float*)d_in[4];
  const float* wp3 = (const float*)d_in[5];
  const float* bp3 = (const float*)d_in[6];
  const float* wu1 = (const float*)d_in[7];
  const float* bu1 = (const float*)d_in[8];
  const float* wu2 = (const float*)d_in[9];
  const float* bu2 = (const float*)d_in[10];
  const float* wu3 = (const float*)d_in[11];
  const float* bu3 = (const float*)d_in[12];
  const float* wu4 = (const float*)d_in[13];
  const float* bu4 = (const float*)d_in[14];
  const int* steps = (const int*)d_in[15];

  short* W1 = (short*)d_ws;          // [2][8][512]
  short* W2 = W1 + 8192;             // [36][8][512]
  short* W3 = W2 + 147456;           // 4 x [4][8][512] contiguous
  short* W4 = W3 + 16384;
  short* W5 = W4 + 16384;
  short* W6 = W5 + 16384;
  short* W7 = W6 + 16384;            // [4][1][512]

  prepack_kernel<<<(8192   + 255) / 256, 256, 0, stream>>>(wp1, W1, 1, 8, 45,   128, 8192);
  prepack_kernel<<<(147456 + 255) / 256, 256, 0, stream>>>(wp2, W2, 2, 8, 1152, 128, 147456);
  prepack_kernel<<<(16384  + 255) / 256, 256, 0, stream>>>(wp3, W3, 0, 8, 128,  128, 16384);
  prepack_kernel<<<(16384  + 255) / 256, 256, 0, stream>>>(wu1, W4, 0, 8, 128,  128, 16384);
  prepack_kernel<<<(16384  + 255) / 256, 256, 0, stream>>>(wu2, W5, 0, 8, 128,  128, 16384);
  prepack_kernel<<<(16384  + 255) / 256, 256, 0, stream>>>(wu3, W6, 0, 8, 128,  128, 16384);
  prepack_kernel<<<(2048   + 255) / 256, 256, 0, stream>>>(wu4, W7, 0, 1, 128,  5,   2048);

  nca_kernel<<<NSAMPLES, 512, 0, stream>>>(
      x, bp1, bp2, bp3, bu1, bu2, bu3, bu4,
      W1, W2, W3, W7, steps, (float*)d_out);
}

// Round 10
// 4881.342 us; speedup vs baseline: 1.1968x; 1.1968x over previous
//
#include <hip/hip_runtime.h>
#include <cstdint>
#include <cstddef>

// SokobanNCA v10: r6 base (256 thr, 2 WG/CU, transient weights, pk2, XOR
// addressing) with 2x2 wave partition: wave (mh,qh), mh = c_out tiles
// 4mh..4mh+3, qh = qt half {0..3}/{4..6}. Each activation B-fragment read by
// 2 waves instead of 4 -> LDS read traffic halves; MFMA becomes binding pipe.

#define NSAMPLES 2048
#define ZROW_BASE 28672          // 112*256
#define HA_OFF 0
#define HB_OFF 28928             // 113*256
#define A1_OFF HB_OFF            // A1 aliases hB (disjoint lifetime)
#define XS_OFF 57600             // HB_OFF + 112*256
#define LDS_TOTAL 62976          // XS_OFF + 112*48

typedef __attribute__((ext_vector_type(8))) short bf16x8;
typedef __attribute__((ext_vector_type(4))) float f32x4;
typedef __attribute__((ext_vector_type(2))) unsigned int u32x2;
typedef __attribute__((ext_vector_type(4))) unsigned int u32x4;

#define MFMA16(A,B,C) __builtin_amdgcn_mfma_f32_16x16x32_bf16((A),(B),(C),0,0,0)

__device__ __forceinline__ unsigned pk2(float a, float b) {
  unsigned r;
  asm("v_cvt_pk_bf16_f32 %0, %1, %2" : "=v"(r) : "v"(a), "v"(b));
  return r;
}
__device__ __forceinline__ unsigned pk2r(float a, float b) {
  return pk2(fmaxf(a, 0.f), fmaxf(b, 0.f));
}

__device__ __forceinline__ short f2bf(float f) {
  unsigned u = __float_as_uint(f);
  return (short)((u + 0x7FFFu + ((u >> 16) & 1u)) >> 16);  // RNE
}

// ---------------- weight pre-pack (unchanged; validated r1-r9) ----------------
__global__ void prepack_kernel(const float* __restrict__ w, short* __restrict__ dst,
                               int mode, int ntc, int Kact, int Nact, int total) {
  int idx = blockIdx.x * 256 + threadIdx.x;
  if (idx >= total) return;
  int j = idx & 7, l = (idx >> 3) & 63, t = idx >> 9;
  int nt = t % ntc, kt = t / ntc;
  int kg = kt * 32 + (l >> 4) * 8 + j;
  int nn = nt * 16 + (l & 15);
  float v = 0.f;
  if (mode == 0) {
    if (kg < Kact && nn < Nact) v = w[nn * Kact + kg];
  } else if (mode == 1) {
    if (kg < 45) { int s = kg / 5, cin = kg - 5 * s; v = w[nn * 45 + cin * 9 + s]; }
  } else {
    int s = kt >> 2;
    int kk = (kt & 3) * 32 + (l >> 4) * 8 + j;
    v = w[nn * 1152 + kk * 9 + s];
  }
  dst[idx] = f2bf(v);
}

// ---------------- main kernel ----------------
__global__ __launch_bounds__(256, 2)
void nca_kernel(
    const float* __restrict__ x_in,
    const float* __restrict__ b1p, const float* __restrict__ b2p,
    const float* __restrict__ b3p, const float* __restrict__ b4p,
    const float* __restrict__ b5p, const float* __restrict__ b6p,
    const float* __restrict__ b7p,
    const short* __restrict__ W1, const short* __restrict__ W2,
    const short* __restrict__ W3,   // W3..W6 contiguous: W3 + li*16384
    const short* __restrict__ W7,
    const int* __restrict__ steps_ptr, float* __restrict__ d_out) {
  __shared__ __align__(16) char lds[LDS_TOTAL];
  float* xs = (float*)(lds + XS_OFF);  // [112][12] f32, rows 48 B

  const int tid = threadIdx.x;
  const int sample = blockIdx.x;
  const int w = tid >> 6;         // wave 0..3
  const int mh = w >> 1;          // c_out quad: tiles 4mh..4mh+3
  const int qh = w & 1;           // pixel half
  const int l = tid & 63;
  const int n = l & 15;
  const int g = l >> 4;
  const int g16 = g << 4;
  const int swzc = (n & 7) << 4;
  const int qtb = qh * 4;         // owned qt base
  const int nq  = qh ? 3 : 4;     // owned qt count
  const int steps = *steps_ptr;
  const float steps_f = (float)steps;
  const f32x4 fz = {0.f, 0.f, 0.f, 0.f};

  // LDS bases (layout identical to r3-r9)
  const int rdA = HA_OFF + n * 256 + (g16 ^ swzc);
  const int rdB = HB_OFF + n * 256 + (g16 ^ swzc);
  const int rd1 = A1_OFF + n * 128 + (g16 ^ swzc);
  const int za  = HA_OFF + ZROW_BASE + g16;
  int wcolv[4];
#pragma unroll
  for (int i = 0; i < 4; ++i)
    wcolv[i] = ((32 * (4 * mh + i)) | (8 * g)) ^ swzc;

  // per-owned-qt pixel geometry (c2 shift masking)
  int rcq[4];
#pragma unroll
  for (int qtl = 0; qtl < 4; ++qtl) {
    int p = 16 * (qtb + qtl) + n;
    if (qtl < nq && p < 100) { int r = p / 10; rcq[qtl] = r * 32 + (p - 10 * r); }
    else rcq[qtl] = 0x4000;
  }
  // strided (c,px) decomposition for 500-elem copies
  const int cA = tid / 100, pA = tid - 100 * cA;
  const int cB = (tid + 256) / 100, pB = tid + 256 - 100 * cB;
  const int offA = pA * 12 + cA, offB = pB * 12 + cB;

  // zero ZROW of hA
  if (tid < 64) *(unsigned*)(lds + HA_OFF + ZROW_BASE + tid * 4) = 0;
  // load x state
  xs[offA] = x_in[(size_t)sample * 500 + tid];
  if (tid < 244) xs[offB] = x_in[(size_t)sample * 500 + tid + 256];
  // resident c7 bias (tiny)
  f32x4 b7v = fz;
  if (g == 0) b7v = *(const f32x4*)&b7p[0];
  else if (g == 1) b7v.x = b7p[4];
  __syncthreads();

  for (int step = 0; step < steps; ++step) {
    // ---- phase A: copy out states[step-1]; build im2col (r6-validated) ----
    if (step > 0) {
      size_t sb = 1024000u + ((size_t)(step - 1) * NSAMPLES + sample) * 500u;
      __builtin_nontemporal_store(xs[offA], &d_out[sb + tid]);
      if (tid < 244) __builtin_nontemporal_store(xs[offB], &d_out[sb + tid + 256]);
    }
    if (tid < 112) {
      const int p = tid;
      const bool pv = p < 100;
      const int pc = pv ? p : 99;
      const int r = pc / 10, c0 = pc - 10 * r;
      float val[48];
#pragma unroll
      for (int s = 0; s < 9; ++s) {
        const int dr = s / 3 - 1, dc = s % 3 - 1;
        f32x4 xv = fz; float x4v = 0.f;
        if (pv && (unsigned)(r + dr) < 10u && (unsigned)(c0 + dc) < 10u) {
          const float* xr = &xs[(p + dr * 10 + dc) * 12];
          xv = *(const f32x4*)xr; x4v = xr[4];
        }
        val[5*s+0] = xv.x; val[5*s+1] = xv.y; val[5*s+2] = xv.z;
        val[5*s+3] = xv.w; val[5*s+4] = x4v;
      }
      val[45] = val[46] = val[47] = 0.f;
      unsigned wd[24];
#pragma unroll
      for (int i = 0; i < 24; ++i) wd[i] = pk2(val[2*i], val[2*i+1]);
      const int swzr = (p & 7) << 4;
      char* arow = lds + A1_OFF + p * 128;
#pragma unroll
      for (int j = 0; j < 6; ++j) {
        u32x4 wv = {wd[4*j], wd[4*j+1], wd[4*j+2], wd[4*j+3]};
        *(u32x4*)(arow + ((16 * j) ^ swzr)) = wv;
      }
      u32x4 z4 = {0, 0, 0, 0};
      *(u32x4*)(arow + (96 ^ swzr)) = z4;
      *(u32x4*)(arow + (112 ^ swzr)) = z4;
    }
    __syncthreads();

    // ---- c1: A1 @ W1 (K=64) -> hA (4 mt tiles, own qt half) ----
    {
      f32x4 acc[4][4];
#pragma unroll
      for (int i = 0; i < 4; ++i) {
        f32x4 pb = *(const f32x4*)&b1p[16 * (4 * mh + i) + 4 * g];
#pragma unroll
        for (int qtl = 0; qtl < 4; ++qtl) acc[i][qtl] = pb;
      }
#pragma unroll
      for (int kt = 0; kt < 2; ++kt) {
        bf16x8 Wf[4];
#pragma unroll
        for (int i = 0; i < 4; ++i)
          Wf[i] = *(const bf16x8*)&W1[((kt * 8 + 4 * mh + i) * 64 + l) * 8];
        const char* src = lds + (rd1 ^ (kt << 6));
#pragma unroll
        for (int qtl = 0; qtl < 4; ++qtl) {
          if (qtl < nq) {
            bf16x8 Bf = *(const bf16x8*)(src + (qtb + qtl) * 2048);
#pragma unroll
            for (int i = 0; i < 4; ++i) acc[i][qtl] = MFMA16(Wf[i], Bf, acc[i][qtl]);
          }
        }
      }
#pragma unroll
      for (int qtl = 0; qtl < 4; ++qtl) {
        if (qtl < nq) {
          int row = (16 * (qtb + qtl) + n) * 256;
#pragma unroll
          for (int i = 0; i < 4; ++i) {
            f32x4 v = acc[i][qtl];
            u32x2 wv = {pk2r(v.x, v.y), pk2r(v.z, v.w)};
            *(u32x2*)(lds + HA_OFF + row + wcolv[i]) = wv;
          }
        }
      }
    }
    __syncthreads();

    // ---- c2: 3x3 shift-decomposed, runtime s-loop ----
    {
      f32x4 acc[4][4];
#pragma unroll
      for (int i = 0; i < 4; ++i) {
        f32x4 pb = *(const f32x4*)&b2p[16 * (4 * mh + i) + 4 * g];
#pragma unroll
        for (int qtl = 0; qtl < 4; ++qtl) acc[i][qtl] = pb;
      }
#pragma unroll 1
      for (int s = 0; s < 9; ++s) {
        const int s3 = s / 3;
        const int dr = s3 - 1, dc = s - 3 * s3 - 1;
        const int ps = n + dr * 10 + dc;
        const int bs = HA_OFF + ps * 256 + (g16 ^ ((ps & 7) << 4));
        int va[4];
#pragma unroll
        for (int qtl = 0; qtl < 4; ++qtl) {
          bool ok = ((unsigned)((rcq[qtl] >> 5) + dr) < 10u) &&
                    ((unsigned)((rcq[qtl] & 31) + dc) < 10u);
          va[qtl] = ok ? (bs + (qtb + qtl) * 4096) : za;
        }
        const short* Wsl = W2 + s * 16384;
#pragma unroll
        for (int kt = 0; kt < 4; ++kt) {
          bf16x8 Wf[4];
#pragma unroll
          for (int i = 0; i < 4; ++i)
            Wf[i] = *(const bf16x8*)&Wsl[((kt * 8 + 4 * mh + i) * 64 + l) * 8];
#pragma unroll
          for (int qtl = 0; qtl < 4; ++qtl) {
            if (qtl < nq) {
              bf16x8 Bf = *(const bf16x8*)(lds + (va[qtl] ^ (kt << 6)));
#pragma unroll
              for (int i = 0; i < 4; ++i) acc[i][qtl] = MFMA16(Wf[i], Bf, acc[i][qtl]);
            }
          }
        }
      }
#pragma unroll
      for (int qtl = 0; qtl < 4; ++qtl) {
        if (qtl < nq) {
          int row = (16 * (qtb + qtl) + n) * 256;
#pragma unroll
          for (int i = 0; i < 4; ++i) {
            f32x4 v = acc[i][qtl];
            u32x2 wv = {pk2r(v.x, v.y), pk2r(v.z, v.w)};
            *(u32x2*)(lds + HB_OFF + row + wcolv[i]) = wv;
          }
        }
      }
    }
    __syncthreads();

    // ---- c3..c6: runtime layer loop, ping-pong hB<->hA ----
#pragma unroll 1
    for (int li = 0; li < 4; ++li) {
      const float* bp = (li == 0) ? b3p : (li == 1) ? b4p : (li == 2) ? b5p : b6p;
      const int rdb = (li & 1) ? rdA : rdB;
      const int dsto = (li & 1) ? HB_OFF : HA_OFF;
      const short* Wp = W3 + li * 16384;
      f32x4 acc[4][4];
#pragma unroll
      for (int i = 0; i < 4; ++i) {
        f32x4 pb = *(const f32x4*)&bp[16 * (4 * mh + i) + 4 * g];
#pragma unroll
        for (int qtl = 0; qtl < 4; ++qtl) acc[i][qtl] = pb;
      }
#pragma unroll
      for (int kt = 0; kt < 4; ++kt) {
        bf16x8 Wf[4];
#pragma unroll
        for (int i = 0; i < 4; ++i)
          Wf[i] = *(const bf16x8*)&Wp[((kt * 8 + 4 * mh + i) * 64 + l) * 8];
        const char* src = lds + (rdb ^ (kt << 6));
#pragma unroll
        for (int qtl = 0; qtl < 4; ++qtl) {
          if (qtl < nq) {
            bf16x8 Bf = *(const bf16x8*)(src + (qtb + qtl) * 4096);
#pragma unroll
            for (int i = 0; i < 4; ++i) acc[i][qtl] = MFMA16(Wf[i], Bf, acc[i][qtl]);
          }
        }
      }
#pragma unroll
      for (int qtl = 0; qtl < 4; ++qtl) {
        if (qtl < nq) {
          int row = (16 * (qtb + qtl) + n) * 256;
#pragma unroll
          for (int i = 0; i < 4; ++i) {
            f32x4 v = acc[i][qtl];
            u32x2 wv = {pk2r(v.x, v.y), pk2r(v.z, v.w)};
            *(u32x2*)(lds + dsto + row + wcolv[i]) = wv;
          }
        }
      }
      __syncthreads();
    }

    // ---- c7 (128->5) + residual + softmax (r6-validated, W7f transient) ----
    {
      bf16x8 W7f[4];
#pragma unroll
      for (int kt = 0; kt < 4; ++kt)
        W7f[kt] = *(const bf16x8*)&W7[(kt * 64 + l) * 8];
      float invT = 1.f / fmaxf(1.f - (float)step / steps_f, 0.5f);
#pragma unroll
      for (int rep = 0; rep < 2; ++rep) {
        int qt = 2 * w + rep;
        if (qt < 7) {
          f32x4 a = b7v;
          int va7 = rdB + qt * 4096;
#pragma unroll
          for (int kt = 0; kt < 4; ++kt) {
            bf16x8 Bf = *(const bf16x8*)(lds + (va7 ^ (kt << 6)));
            a = MFMA16(W7f[kt], Bf, a);
          }
          float c4v = __shfl_xor(a.x, 16);
          int px = 16 * qt + n;
          if (g == 0 && px < 100) {
            float* xr = &xs[px * 12];
            f32x4 xo = *(f32x4*)xr; float x4 = xr[4];
            float v0 = (xo.x + a.x) * invT, v1 = (xo.y + a.y) * invT;
            float v2 = (xo.z + a.z) * invT, v3 = (xo.w + a.w) * invT;
            float v4 = (x4 + c4v) * invT;
            float m = fmaxf(fmaxf(fmaxf(v0, v1), fmaxf(v2, v3)), v4);
            float e0 = __expf(v0 - m), e1 = __expf(v1 - m), e2 = __expf(v2 - m);
            float e3 = __expf(v3 - m), e4 = __expf(v4 - m);
            float inv = 1.f / (e0 + e1 + e2 + e3 + e4);
            f32x4 pv = {e0 * inv, e1 * inv, e2 * inv, e3 * inv};
            *(f32x4*)xr = pv; xr[4] = e4 * inv;
          }
        }
      }
    }
    __syncthreads();
  }

  // ---- final outputs: x_final + states[steps-1] (nontemporal) ----
  {
    size_t sb = 1024000u + ((size_t)(steps - 1) * NSAMPLES + sample) * 500u;
    size_t fb = (size_t)sample * 500u;
    float vA = xs[offA];
    __builtin_nontemporal_store(vA, &d_out[fb + tid]);
    __builtin_nontemporal_store(vA, &d_out[sb + tid]);
    if (tid < 244) {
      float vB = xs[offB];
      __builtin_nontemporal_store(vB, &d_out[fb + tid + 256]);
      __builtin_nontemporal_store(vB, &d_out[sb + tid + 256]);
    }
  }
}

// ---------------- launch ----------------
extern "C" void kernel_launch(void* const* d_in, const int* in_sizes, int n_in,
                              void* d_out, int out_size, void* d_ws, size_t ws_size,
                              hipStream_t stream) {
  const float* x   = (const float*)d_in[0];
  const float* wp1 = (const float*)d_in[1];
  const float* bp1 = (const float*)d_in[2];
  const float* wp2 = (const float*)d_in[3];
  const float* bp2 = (const float*)d_in[4];
  const float* wp3 = (const float*)d_in[5];
  const float* bp3 = (const float*)d_in[6];
  const float* wu1 = (const float*)d_in[7];
  const float* bu1 = (const float*)d_in[8];
  const float* wu2 = (const float*)d_in[9];
  const float* bu2 = (const float*)d_in[10];
  const float* wu3 = (const float*)d_in[11];
  const float* bu3 = (const float*)d_in[12];
  const float* wu4 = (const float*)d_in[13];
  const float* bu4 = (const float*)d_in[14];
  const int* steps = (const int*)d_in[15];

  short* W1 = (short*)d_ws;          // [2][8][512]
  short* W2 = W1 + 8192;             // [36][8][512]
  short* W3 = W2 + 147456;           // 4 x [4][8][512] contiguous
  short* W4 = W3 + 16384;
  short* W5 = W4 + 16384;
  short* W6 = W5 + 16384;
  short* W7 = W6 + 16384;            // [4][1][512]

  prepack_kernel<<<(8192   + 255) / 256, 256, 0, stream>>>(wp1, W1, 1, 8, 45,   128, 8192);
  prepack_kernel<<<(147456 + 255) / 256, 256, 0, stream>>>(wp2, W2, 2, 8, 1152, 128, 147456);
  prepack_kernel<<<(16384  + 255) / 256, 256, 0, stream>>>(wp3, W3, 0, 8, 128,  128, 16384);
  prepack_kernel<<<(16384  + 255) / 256, 256, 0, stream>>>(wu1, W4, 0, 8, 128,  128, 16384);
  prepack_kernel<<<(16384  + 255) / 256, 256, 0, stream>>>(wu2, W5, 0, 8, 128,  128, 16384);
  prepack_kernel<<<(16384  + 255) / 256, 256, 0, stream>>>(wu3, W6, 0, 8, 128,  128, 16384);
  prepack_kernel<<<(2048   + 255) / 256, 256, 0, stream>>>(wu4, W7, 0, 1, 128,  5,   2048);

  nca_kernel<<<NSAMPLES, 256, 0, stream>>>(
      x, bp1, bp2, bp3, bu1, bu2, bu3, bu4,
      W1, W2, W3, W7, steps, (float*)d_out);
}